// Round 1
// baseline (233.879 us; speedup 1.0000x reference)
//
#include <hip/hip_runtime.h>
#include <stdint.h>

#define VOCAB_N   200000
#define EMBED_DIM 128
#define N_POS     10
#define N_NEG     64
#define N_ROWS    (1 + N_POS + N_NEG)          // 75 one-hot rows
#define TOT_FLOATS (N_ROWS * VOCAB_N)          // 15,000,000
#define THREADS_SCAN (TOT_FLOATS / 8)          // 1,875,000 (8 floats = 32 B/thread)
#define SCAN_BLOCKS ((THREADS_SCAN + 255) / 256)  // 7325

// Publication protocol: finder stores (idx | TAG) with agent-scope release.
// TAG = bit30: clear in 0xAAAAAAAA poison AND in zero-init; idx < 2^18 so the
// payload never sets it. Loss block spins per-slot until TAG appears.
// No inter-block barrier -> deadlock-free under any dispatch order.
#define TAG  0x40000000
#define MASK 0x3FFFFFFF

__global__ void __launch_bounds__(256)
k_fused(const float* __restrict__ cbuf,
        const float* __restrict__ pbuf,
        const float* __restrict__ nbuf,
        const float* __restrict__ iemb,   // [128, VOCAB_N]
        const float* __restrict__ oemb,   // [VOCAB_N, 128]
        int* __restrict__ ws,             // [75] published idx slots
        float* __restrict__ out) {
    if (blockIdx.x != 0) {
        // ---------------- scan role (blocks 1..SCAN_BLOCKS) ----------------
        const int g = (int)(blockIdx.x - 1) * 256 + (int)threadIdx.x;
        if (g >= THREADS_SCAN) return;
        const int f0 = g * 8;                  // flat float index, concatenated space
        // Buffer boundaries (200000, 2,200,000) are multiples of 8 -> no straddling.
        const float* src;
        int off;
        if (f0 < VOCAB_N)                    { src = cbuf; off = f0; }
        else if (f0 < (1 + N_POS) * VOCAB_N) { src = pbuf; off = f0 - VOCAB_N; }
        else                                 { src = nbuf; off = f0 - (1 + N_POS) * VOCAB_N; }

        const uint4 a = *reinterpret_cast<const uint4*>(src + off);
        const uint4 b = *reinterpret_cast<const uint4*>(src + off + 4);
        // Fast common-path rejection: almost every thread sees 8 zeros.
        if ((a.x | a.y | a.z | a.w | b.x | b.y | b.z | b.w) == 0u) return;
        const uint32_t w[8] = {a.x, a.y, a.z, a.w, b.x, b.y, b.z, b.w};
#pragma unroll
        for (int j = 0; j < 8; ++j) {
            if (w[j]) {
                const int gf = f0 + j;
                __hip_atomic_store(&ws[gf / VOCAB_N], (gf % VOCAB_N) | TAG,
                                   __ATOMIC_RELEASE, __HIP_MEMORY_SCOPE_AGENT);
            }
        }
        return;
    }

    // ---------------- loss role (block 0, scheduled first: overlaps scan) ----
    __shared__ float v[EMBED_DIM];
    __shared__ float wave_sum[4];
    const int t = threadIdx.x;
    const int wave = t >> 6;
    const int lane = t & 63;

    // 1) Wait only for the center index (cbuf is scanned by the first ~98
    //    scan blocks -> published within the first microsecond).
    int w0;
    do {
        w0 = __hip_atomic_load(&ws[0], __ATOMIC_ACQUIRE, __HIP_MEMORY_SCOPE_AGENT);
        if (!(w0 & TAG)) __builtin_amdgcn_s_sleep(1);
    } while (!(w0 & TAG));
    const int c = w0 & MASK;
    if (t < EMBED_DIM)
        v[t] = iemb[(size_t)t * VOCAB_N + c];  // center embedding column
    __syncthreads();

    const float vl0 = v[lane];
    const float vl1 = v[lane + 64];
    float local_sum = 0.f;

    // 2) Per-p spin inside the loop: each dot-product runs as soon as its
    //    index is published, overlapping the remaining scan instead of
    //    waiting for all 75 and paying a serial ~5us tail afterwards.
    for (int p = wave; p < N_POS + N_NEG; p += 4) {
        int w;
        do {
            // all 64 lanes poll the same word -> HW broadcast, branch uniform
            w = __hip_atomic_load(&ws[1 + p], __ATOMIC_ACQUIRE, __HIP_MEMORY_SCOPE_AGENT);
            if (!(w & TAG)) __builtin_amdgcn_s_sleep(1);
        } while (!(w & TAG));
        const int e = w & MASK;
        float a0, a1;
        if (p < N_POS) {
            // positive: column e of input_emb (stride VOCAB_N)
            a0 = iemb[(size_t)lane * VOCAB_N + e];
            a1 = iemb[(size_t)(lane + 64) * VOCAB_N + e];
        } else {
            // negative: row e of output_emb (contiguous)
            a0 = oemb[(size_t)e * EMBED_DIM + lane];
            a1 = oemb[(size_t)e * EMBED_DIM + lane + 64];
        }
        float d = a0 * vl0 + a1 * vl1;
#pragma unroll
        for (int off = 32; off > 0; off >>= 1)
            d += __shfl_down(d, off, 64);
        if (lane == 0) {
            const float x = (p < N_POS) ? d : -d;
            const float ls = (x >= 0.f) ? -log1pf(expf(-x))
                                        : (x - log1pf(expf(x)));
            local_sum += ls;
        }
    }

    if (lane == 0) wave_sum[wave] = local_sum;
    __syncthreads();
    if (t == 0)
        out[0] = -(wave_sum[0] + wave_sum[1] + wave_sum[2] + wave_sum[3]);
}

extern "C" void kernel_launch(void* const* d_in, const int* in_sizes, int n_in,
                              void* d_out, int out_size, void* d_ws, size_t ws_size,
                              hipStream_t stream) {
    const float* center = (const float*)d_in[0];
    const float* pos    = (const float*)d_in[1];
    const float* neg    = (const float*)d_in[2];
    const float* iemb   = (const float*)d_in[3];
    const float* oemb   = (const float*)d_in[4];
    int* ws = (int*)d_ws;   // 75 tagged idx words, each published exactly once per call

    k_fused<<<SCAN_BLOCKS + 1, 256, 0, stream>>>(center, pos, neg, iemb, oemb,
                                                 ws, (float*)d_out);
}